// Round 11
// baseline (272.712 us; speedup 1.0000x reference)
//
#include <hip/hip_runtime.h>
#include <hip/hip_bf16.h>

// ---------------------------------------------------------------------------
// AMMN_Net: dual 2-layer GCN + gated fusion head.
// R11 = R10 + pipelined gather aggregation:
//  - k_agg: global_load_lds 4-deep pipeline (LDS-buffered MLP, zero VGPR
//    cost), counted vmcnt(3), 128-thr blocks (2 indep waves, 8 nodes).
//    Edge stream = [self]+cols; col int4 in regs, per-batch index via shfl.
//  - dinv folded into features (k_xconv: x*dinv; k_bnfold: relu(bn(h))*dinv)
//    -> agg passes are PURE gather-sums (no per-edge dinv load / BN VALU).
//  - rest identical to R10: bucketed ELL build, MFMA GEMMs (swapped ops),
//    BN stats fused in GEMM1, bf16 nodes, fully fused head. 10 launches.
// ---------------------------------------------------------------------------

#define ELL_CAP 64
#define BCAP 8192
#define ACHUNK 5120

typedef __attribute__((ext_vector_type(8))) short short8v;   // 8 bf16
typedef __attribute__((ext_vector_type(4))) float f32x4;

static __device__ __forceinline__ unsigned short f2bf(float f) {
  unsigned u = __float_as_uint(f);
  unsigned r = (u + 0x7fffu + ((u >> 16) & 1u)) >> 16;  // RNE
  return (unsigned short)r;
}
static __device__ __forceinline__ unsigned packbf(float a, float b) {
  return (unsigned)f2bf(a) | ((unsigned)f2bf(b) << 16);
}
static __device__ __forceinline__ float bflo(unsigned u) {
  return __uint_as_float(u << 16);
}
static __device__ __forceinline__ float bfhi(unsigned u) {
  return __uint_as_float(u & 0xffff0000u);
}
static __device__ __forceinline__ float bf2f(short s) {
  return __uint_as_float((unsigned)(unsigned short)s << 16);
}

static __device__ __forceinline__ void gload16(const unsigned* g, unsigned* l) {
  __builtin_amdgcn_global_load_lds(
      (const __attribute__((address_space(1))) unsigned*)g,
      (__attribute__((address_space(3))) unsigned*)l, 16, 0, 0);
}

// prep: pack Wb1/Wb2(block-diag)/WbH bf16 [k/8][128][8]; biases; init
// gbump + stats. (x conversion moved to k_xconv, after csrB.)
__global__ void k_prep(int* __restrict__ gbump, float* __restrict__ stats,
                       const float* __restrict__ W1g, const float* __restrict__ b1g,
                       const float* __restrict__ W1s, const float* __restrict__ b1s,
                       const float* __restrict__ W2g, const float* __restrict__ b2g,
                       const float* __restrict__ W2s, const float* __restrict__ b2s,
                       const float* __restrict__ Wf1,
                       short* __restrict__ Wb1, short* __restrict__ Wb2,
                       short* __restrict__ WbH, float* __restrict__ bc1,
                       float* __restrict__ bc2, int NB) {
  int idx = blockIdx.x * 256 + threadIdx.x;
  if (idx < 16384) {
    int k = idx >> 7, c = idx & 127;
    int pi = (k >> 3) * 1024 + c * 8 + (k & 7);  // [k/8][c][k&7]
    float w1 = (c < 64) ? W1g[k * 64 + c] : W1s[k * 64 + (c - 64)];
    Wb1[pi] = (short)f2bf(w1);
    float w2 = 0.f;
    if (k < 64 && c < 64) w2 = W2g[k * 64 + c];
    else if (k >= 64 && c >= 64) w2 = W2s[(k - 64) * 64 + (c - 64)];
    Wb2[pi] = (short)f2bf(w2);
    WbH[pi] = (short)f2bf(Wf1[k * 128 + c]);
  }
  if (idx < 128) {
    bc1[idx] = (idx < 64) ? b1g[idx] : b1s[idx - 64];
    bc2[idx] = (idx < 64) ? b2g[idx] : b2s[idx - 64];
  }
  if (idx < NB) gbump[idx] = idx * BCAP;
  if (idx < 2048) stats[idx] = 0.f;
}

// Pass A: bucket edges by dst>>8 (one global atomic per block-bucket)
__global__ __launch_bounds__(256) void k_bucketA(
    const int* __restrict__ src, const int* __restrict__ dst,
    int* __restrict__ gbump, unsigned* __restrict__ ebuf, int E, int NB) {
  __shared__ int hist[512];
  __shared__ int gbase[512];
  int t = threadIdx.x;
  int e0 = blockIdx.x * ACHUNK;
  int m = min(ACHUNK, E - e0);
  for (int b = t; b < NB; b += 256) hist[b] = 0;
  __syncthreads();
  for (int i = t; i < m; i += 256) atomicAdd(&hist[dst[e0 + i] >> 8], 1);
  __syncthreads();
  for (int b = t; b < NB; b += 256) {
    gbase[b] = hist[b] ? atomicAdd(&gbump[b], hist[b]) : 0;
    hist[b] = 0;
  }
  __syncthreads();
  for (int i = t; i < m; i += 256) {
    int d = dst[e0 + i];
    int s = src[e0 + i];
    int b = d >> 8;
    int off = gbase[b] + atomicAdd(&hist[b], 1);
    if (off < (b + 1) * BCAP)
      ebuf[off] = ((unsigned)s << 8) | (unsigned)(d & 255);
  }
}

// Pass B: block-per-bucket; LDS bump -> ELL col + capped cnt + dinv
__global__ __launch_bounds__(256) void k_csrB(
    const unsigned* __restrict__ ebuf, const int* __restrict__ gbump,
    int* __restrict__ cnt, float* __restrict__ dinv, int* __restrict__ col,
    int n) {
  __shared__ int lbump[256];
  int b = blockIdx.x;
  lbump[threadIdx.x] = 0;
  __syncthreads();
  int base = b * BCAP;
  int m = min(gbump[b] - base, BCAP);
  for (int i = threadIdx.x; i < m; i += 256) {
    unsigned p = ebuf[base + i];
    int dloc = p & 255;
    int slot = atomicAdd(&lbump[dloc], 1);
    if (slot < ELL_CAP)
      col[(b * 256 + dloc) * ELL_CAP + slot] = (int)(p >> 8);
  }
  __syncthreads();
  int node = b * 256 + threadIdx.x;
  if (node < n) {
    int c = lbump[threadIdx.x];
    cnt[node] = min(c, ELL_CAP);
    dinv[node] = rsqrtf((float)(c + 1));  // true degree for norm
  }
}

// x (fp32) -> bf16 feat' = x * dinv[row]
__global__ void k_xconv(const float* __restrict__ x, const float* __restrict__ dinv,
                        unsigned* __restrict__ outp, int n16) {
  int i = blockIdx.x * 256 + threadIdx.x;
  if (i >= n16) return;
  float dv = dinv[i >> 4];
  const float4* f4 = (const float4*)x;
  float4 a = f4[i * 2], b = f4[i * 2 + 1];
  uint4 o;
  o.x = packbf(a.x * dv, a.y * dv);
  o.y = packbf(a.z * dv, a.w * dv);
  o.z = packbf(b.x * dv, b.y * dv);
  o.w = packbf(b.z * dv, b.w * dv);
  ((uint4*)outp)[i] = o;
}

// hb (bf16) -> bf16 feat2' = relu(bn(h)) * dinv[row]  (stats from GEMM1)
__global__ void k_bnfold(const unsigned* __restrict__ hb,
                         const float* __restrict__ stats,
                         const float* __restrict__ g1g, const float* __restrict__ be1g,
                         const float* __restrict__ g1s, const float* __restrict__ be1s,
                         const float* __restrict__ dinv,
                         unsigned* __restrict__ outp, float inv_n, int n16) {
  __shared__ float sc_sh[128], sf_sh[128];
  {
    int c = threadIdx.x;
    if (c < 128) {
      float s = 0.f, q = 0.f;
#pragma unroll
      for (int k = 0; k < 8; k++) {
        s += stats[k * 256 + c];
        q += stats[k * 256 + 128 + c];
      }
      float mu = s * inv_n;
      float var = q * inv_n - mu * mu;
      float gam = (c < 64) ? g1g[c] : g1s[c - 64];
      float bet = (c < 64) ? be1g[c] : be1s[c - 64];
      float scv = gam * rsqrtf(var + 1e-5f);
      sc_sh[c] = scv;
      sf_sh[c] = bet - mu * scv;
    }
    __syncthreads();
  }
  int i = blockIdx.x * 256 + threadIdx.x;
  if (i >= n16) return;
  float dv = dinv[i >> 4];
  int c8 = (i & 15) * 8;
  uint4 v = ((const uint4*)hb)[i];
  float f[8] = {bflo(v.x), bfhi(v.x), bflo(v.y), bfhi(v.y),
                bflo(v.z), bfhi(v.z), bflo(v.w), bfhi(v.w)};
  uint4 o;
  float o0, o1;
  o0 = fmaxf(f[0] * sc_sh[c8 + 0] + sf_sh[c8 + 0], 0.f) * dv;
  o1 = fmaxf(f[1] * sc_sh[c8 + 1] + sf_sh[c8 + 1], 0.f) * dv;
  o.x = packbf(o0, o1);
  o0 = fmaxf(f[2] * sc_sh[c8 + 2] + sf_sh[c8 + 2], 0.f) * dv;
  o1 = fmaxf(f[3] * sc_sh[c8 + 3] + sf_sh[c8 + 3], 0.f) * dv;
  o.y = packbf(o0, o1);
  o0 = fmaxf(f[4] * sc_sh[c8 + 4] + sf_sh[c8 + 4], 0.f) * dv;
  o1 = fmaxf(f[5] * sc_sh[c8 + 5] + sf_sh[c8 + 5], 0.f) * dv;
  o.z = packbf(o0, o1);
  o0 = fmaxf(f[6] * sc_sh[c8 + 6] + sf_sh[c8 + 6], 0.f) * dv;
  o1 = fmaxf(f[7] * sc_sh[c8 + 7] + sf_sh[c8 + 7], 0.f) * dv;
  o.w = packbf(o0, o1);
  ((uint4*)outp)[i] = o;
}

// Pipelined pure gather-sum aggregation.
// out[i] = bf16( dinv[i] * sum_{s in [i]+cols(i)} feat'[s] ), feat' pre-scaled.
// 2 waves/block, 4 nodes/wave (16 lanes each). 4-deep global_load_lds
// pipeline: batch b = 4 rows (1/group), slot b&3 in LDS, vmcnt(3) gate.
__global__ __launch_bounds__(128) void k_agg(
    const unsigned* __restrict__ featp, unsigned* __restrict__ outb,
    const int* __restrict__ cnt, const float* __restrict__ dinv,
    const int* __restrict__ col, int n) {
  __shared__ __align__(16) unsigned fbuf[2][4][256];  // [wave][slot][1KB]
  int lane = threadIdx.x & 63;
  int wv = threadIdx.x >> 6;
  int g = lane >> 4, t = lane & 15;
  int node = blockIdx.x * 8 + wv * 4 + g;
  int nodec = min(node, n - 1);
  int cn = (node < n) ? cnt[nodec] : 0;
  float di = dinv[nodec];
  int m = cn + 1;                       // stream: [self] + cn edges
  int mm = m;
  mm = max(mm, __shfl_xor(mm, 16, 64));
  mm = max(mm, __shfl_xor(mm, 32, 64));
  int4 creg = ((const int4*)(col + (size_t)nodec * ELL_CAP))[t];  // cols 4t..4t+3
  unsigned* myf = &fbuf[wv][0][0];
  int gsel = g << 4;  // lane holding int4 #0 of this group

  // prologue: issue batches 0..3 (batch 0 = self)
  gload16(featp + (size_t)nodec * 64 + t * 4, myf + 0 * 256);
  {
    int src = __shfl(creg.x, gsel, 64);
    int idx = (1 <= cn && (unsigned)src < (unsigned)n) ? src : 0;
    gload16(featp + (size_t)idx * 64 + t * 4, myf + 1 * 256);
    src = __shfl(creg.y, gsel, 64);
    idx = (2 <= cn && (unsigned)src < (unsigned)n) ? src : 0;
    gload16(featp + (size_t)idx * 64 + t * 4, myf + 2 * 256);
    src = __shfl(creg.z, gsel, 64);
    idx = (3 <= cn && (unsigned)src < (unsigned)n) ? src : 0;
    gload16(featp + (size_t)idx * 64 + t * 4, myf + 3 * 256);
  }

  float acc[8] = {0.f, 0.f, 0.f, 0.f, 0.f, 0.f, 0.f, 0.f};
  for (int p0 = 0; p0 < mm; p0 += 4) {
#pragma unroll
    for (int u = 0; u < 4; u++) {
      int p = p0 + u;
      if (p >= mm) break;  // wave-uniform
      asm volatile("s_waitcnt vmcnt(3)" ::: "memory");
      __builtin_amdgcn_sched_barrier(0);
      if (p < m) {  // per-group
        uint4 v = *(const uint4*)(myf + u * 256 + lane * 4);
        acc[0] += bflo(v.x); acc[1] += bfhi(v.x);
        acc[2] += bflo(v.y); acc[3] += bfhi(v.y);
        acc[4] += bflo(v.z); acc[5] += bfhi(v.z);
        acc[6] += bflo(v.w); acc[7] += bfhi(v.w);
      }
      // slot u is reused by the next issue: ensure ds_read data landed
      asm volatile("s_waitcnt lgkmcnt(0)" ::: "memory");
      __builtin_amdgcn_sched_barrier(0);
      {
        int b = p + 4;          // batch to issue (dummy row 0 if beyond)
        int e = p + 3;          // its edge index
        int j = (u + 3) & 3;
        int cv = (j == 0) ? creg.x : (j == 1) ? creg.y : (j == 2) ? creg.z : creg.w;
        int src = __shfl(cv, gsel + (e >> 2), 64);
        int idx = (b <= cn && (unsigned)src < (unsigned)n) ? src : 0;
        gload16(featp + (size_t)idx * 64 + t * 4, myf + u * 256);
      }
    }
  }
  asm volatile("s_waitcnt vmcnt(0)" ::: "memory");  // drain before LDS dealloc
  if (node < n) {
    uint4 o;
    o.x = packbf(acc[0] * di, acc[1] * di);
    o.y = packbf(acc[2] * di, acc[3] * di);
    o.z = packbf(acc[4] * di, acc[5] * di);
    o.w = packbf(acc[6] * di, acc[7] * di);
    ((uint4*)outb)[(size_t)node * 16 + t] = o;
  }
}

// MFMA GEMM (swapped operands): lane owns row rowbase+(lane&15),
// cols nt*16+(lane>>4)*4+r. A bf16 row-major [M][128].
// CBF16 -> bf16 row-major C; else fp32.
template <bool CBF16, bool STATS>
__global__ __launch_bounds__(256) void k_mgemm(
    const unsigned* __restrict__ Abf,
    const short* __restrict__ Wb, const float* __restrict__ bias,
    void* __restrict__ Cvp, int M, float* __restrict__ stats) {
  __shared__ short Wl[16384];   // 32 KB
  __shared__ float shs[128], shq[128];
  {
    const uint4* s4 = (const uint4*)Wb;
    uint4* d4 = (uint4*)Wl;
    for (int i = threadIdx.x; i < 2048; i += 256) d4[i] = s4[i];
  }
  if (STATS && threadIdx.x < 128) { shs[threadIdx.x] = 0.f; shq[threadIdx.x] = 0.f; }
  __syncthreads();
  int lane = threadIdx.x & 63;
  int wv = threadIdx.x >> 6;
  int l15 = lane & 15;
  int l4 = lane >> 4;
  int row = blockIdx.x * 64 + wv * 16 + l15;
  int rc = min(row, M - 1);
  bool valid = row < M;

  short8v afr[4];
  const short* Ab = (const short*)Abf + (size_t)rc * 128;
#pragma unroll
  for (int ks = 0; ks < 4; ks++)
    afr[ks] = *(const short8v*)(Ab + ks * 32 + l4 * 8);

  f32x4 acc[8];
#pragma unroll
  for (int nt = 0; nt < 8; nt++) acc[nt] = (f32x4){0.f, 0.f, 0.f, 0.f};
#pragma unroll
  for (int nt = 0; nt < 8; nt++) {
#pragma unroll
    for (int ks = 0; ks < 4; ks++) {
      int kb = ks * 4 + l4;
      short8v w = *(const short8v*)&Wl[kb * 1024 + (nt * 16 + l15) * 8];
      acc[nt] = __builtin_amdgcn_mfma_f32_16x16x32_bf16(w, afr[ks], acc[nt], 0, 0, 0);
    }
  }

#pragma unroll
  for (int nt = 0; nt < 8; nt++) {
    int c0 = nt * 16 + l4 * 4;
    float o[4];
#pragma unroll
    for (int r = 0; r < 4; r++) o[r] = acc[nt][r];
    if (bias) {
      float4 bv = *(const float4*)(bias + c0);
      o[0] += bv.x; o[1] += bv.y; o[2] += bv.z; o[3] += bv.w;
    }
    if (STATS) {
      float s[4], q[4];
#pragma unroll
      for (int r = 0; r < 4; r++) {
        s[r] = valid ? o[r] : 0.f;
        q[r] = s[r] * s[r];
      }
#pragma unroll
      for (int m = 1; m < 16; m <<= 1) {
#pragma unroll
        for (int r = 0; r < 4; r++) {
          s[r] += __shfl_xor(s[r], m, 64);
          q[r] += __shfl_xor(q[r], m, 64);
        }
      }
      if (l15 == 0) {
#pragma unroll
        for (int r = 0; r < 4; r++) {
          atomicAdd(&shs[c0 + r], s[r]);
          atomicAdd(&shq[c0 + r], q[r]);
        }
      }
    }
    if (valid) {
      if (CBF16) {
        unsigned* Cb = (unsigned*)Cvp;
        uint2 p;
        p.x = packbf(o[0], o[1]);
        p.y = packbf(o[2], o[3]);
        *(uint2*)&Cb[(size_t)row * 64 + (c0 >> 1)] = p;
      } else {
        float* Cf = (float*)Cvp;
        *(float4*)&Cf[(size_t)row * 128 + c0] = make_float4(o[0], o[1], o[2], o[3]);
      }
    }
  }
  if (STATS) {
    __syncthreads();
    if (threadIdx.x < 128) {
      float* st = stats + (blockIdx.x & 7) * 256;
      atomicAdd(&st[threadIdx.x], shs[threadIdx.x]);
      atomicAdd(&st[128 + threadIdx.x], shq[threadIdx.x]);
    }
  }
}

// Fused head: both tanh-GEMMs + gate/link/tc epilogue (see R10 notes).
__global__ __launch_bounds__(256) void k_fhead(
    const unsigned short* __restrict__ nodesb,
    const int* __restrict__ users, const int* __restrict__ items,
    const short* __restrict__ WbH, const float* __restrict__ Wsig,
    const float* __restrict__ Wtc, const float* __restrict__ btc,
    const float* __restrict__ Wp, const float* __restrict__ bp,
    float* __restrict__ out, int B) {
  __shared__ short Wl[16384];
  __shared__ float WsigL[256], WpL[256], WtcL[512];
  {
    const uint4* s4 = (const uint4*)WbH;
    uint4* d4 = (uint4*)Wl;
    for (int i = threadIdx.x; i < 2048; i += 256) d4[i] = s4[i];
    if (threadIdx.x < 256) {
      WsigL[threadIdx.x] = Wsig[threadIdx.x];
      WpL[threadIdx.x] = Wp[threadIdx.x];
    }
    for (int i = threadIdx.x; i < 512; i += 256) WtcL[i] = Wtc[i];
  }
  __syncthreads();
  int lane = threadIdx.x & 63;
  int wv = threadIdx.x >> 6;
  int l15 = lane & 15;
  int l4 = lane >> 4;
  int row = blockIdx.x * 64 + wv * 16 + l15;
  int rc = min(row, B - 1);
  int u = users[rc], it = items[rc];
  const short* pu = (const short*)nodesb + u * 128;
  const short* pi = (const short*)nodesb + it * 128;

  short8v ag[4], as[4];
#pragma unroll
  for (int ks = 0; ks < 4; ks++) {
    int k = ks * 32 + l4 * 8;
    const short* pg = (ks < 2) ? (pu + k) : (pi + (k - 64));
    const short* ps = (ks < 2) ? (pu + 64 + k) : (pi + k);
    ag[ks] = *(const short8v*)pg;
    as[ks] = *(const short8v*)ps;
  }

  f32x4 a1[8], a2[8];
#pragma unroll
  for (int nt = 0; nt < 8; nt++) {
    a1[nt] = (f32x4){0.f, 0.f, 0.f, 0.f};
    a2[nt] = (f32x4){0.f, 0.f, 0.f, 0.f};
  }
#pragma unroll
  for (int nt = 0; nt < 8; nt++) {
#pragma unroll
    for (int ks = 0; ks < 4; ks++) {
      int kb = ks * 4 + l4;
      short8v w = *(const short8v*)&Wl[kb * 1024 + (nt * 16 + l15) * 8];
      a1[nt] = __builtin_amdgcn_mfma_f32_16x16x32_bf16(w, ag[ks], a1[nt], 0, 0, 0);
      a2[nt] = __builtin_amdgcn_mfma_f32_16x16x32_bf16(w, as[ks], a2[nt], 0, 0, 0);
    }
  }

  float zp = 0.f;
#pragma unroll
  for (int nt = 0; nt < 8; nt++) {
    int c0 = nt * 16 + l4 * 4;
#pragma unroll
    for (int r = 0; r < 4; r++) {
      float h1 = tanhf(a1[nt][r]);
      float h2 = tanhf(a2[nt][r]);
      a1[nt][r] = h1;
      a2[nt][r] = h2;
      zp += h1 * WsigL[c0 + r] + h2 * WsigL[128 + c0 + r];
    }
  }
  zp += __shfl_xor(zp, 16, 64);
  zp += __shfl_xor(zp, 32, 64);
  float z = 1.f / (1.f + expf(-zp));

  float p0 = 0.f, p1 = 0.f;
#pragma unroll
  for (int nt = 0; nt < 8; nt++) {
    int c0 = nt * 16 + l4 * 4;
#pragma unroll
    for (int r = 0; r < 4; r++) {
      float fu = z * a1[nt][r] + (1.f - z) * a2[nt][r];
      p0 += fu * WpL[(c0 + r) * 2];
      p1 += fu * WpL[(c0 + r) * 2 + 1];
    }
  }
  float t0 = 0.f, t1 = 0.f, t2 = 0.f, t3 = 0.f;
#pragma unroll
  for (int ks = 0; ks < 4; ks++) {
    int kbase = ks * 32 + l4 * 8;
#pragma unroll
    for (int j = 0; j < 8; j++) {
      float gv = bf2f(ag[ks][j]);
      int c = kbase + j;
      t0 += gv * WtcL[c * 4];
      t1 += gv * WtcL[c * 4 + 1];
      t2 += gv * WtcL[c * 4 + 2];
      t3 += gv * WtcL[c * 4 + 3];
    }
  }
  p0 += __shfl_xor(p0, 16, 64); p0 += __shfl_xor(p0, 32, 64);
  p1 += __shfl_xor(p1, 16, 64); p1 += __shfl_xor(p1, 32, 64);
  t0 += __shfl_xor(t0, 16, 64); t0 += __shfl_xor(t0, 32, 64);
  t1 += __shfl_xor(t1, 16, 64); t1 += __shfl_xor(t1, 32, 64);
  t2 += __shfl_xor(t2, 16, 64); t2 += __shfl_xor(t2, 32, 64);
  t3 += __shfl_xor(t3, 16, 64); t3 += __shfl_xor(t3, 32, 64);

  if (l4 == 0 && row < B) {
    out[row * 2] = p0 + bp[0];
    out[row * 2 + 1] = p1 + bp[1];
    float* go = out + 2 * B;
    go[row * 4] = t0 + btc[0];
    go[row * 4 + 1] = t1 + btc[1];
    go[row * 4 + 2] = t2 + btc[2];
    go[row * 4 + 3] = t3 + btc[3];
  }
}

extern "C" void kernel_launch(void* const* d_in, const int* in_sizes, int n_in,
                              void* d_out, int out_size, void* d_ws, size_t ws_size,
                              hipStream_t stream) {
  const float* x = (const float*)d_in[0];
  const int* ei = (const int*)d_in[1];
  const int* users = (const int*)d_in[2];
  const int* items = (const int*)d_in[3];
  const float* W1g = (const float*)d_in[4];
  const float* b1g = (const float*)d_in[5];
  const float* g1g = (const float*)d_in[6];
  const float* be1g = (const float*)d_in[7];
  const float* W2g = (const float*)d_in[8];
  const float* b2g = (const float*)d_in[9];
  const float* W1s = (const float*)d_in[10];
  const float* b1s = (const float*)d_in[11];
  const float* g1s = (const float*)d_in[12];
  const float* be1s = (const float*)d_in[13];
  const float* W2s = (const float*)d_in[14];
  const float* b2s = (const float*)d_in[15];
  const float* Wf1 = (const float*)d_in[16];
  const float* Wsig = (const float*)d_in[17];
  const float* Wtc = (const float*)d_in[18];
  const float* btc = (const float*)d_in[19];
  const float* Wp = (const float*)d_in[20];
  const float* bp = (const float*)d_in[21];

  int n = in_sizes[0] / 128;   // 100000
  int E = in_sizes[1] / 2;     // 1600000
  int B = in_sizes[2];         // 16384
  int NB = (n + 255) >> 8;     // 391
  const int* srcp = ei;
  const int* dstp = ei + E;
  float* out = (float*)d_out;

  char* w = (char*)d_ws;
  auto alloc = [&](size_t bytes) -> char* {
    char* p = w;
    w += (bytes + 255) & ~(size_t)255;
    return p;
  };
  unsigned* xab = (unsigned*)alloc((size_t)n * 64 * 4);     // bf16 agg out
  float* big1 = (float*)alloc((size_t)n * 128 * 4);         // hb bf16 / nodesb bf16
  unsigned* bff = (unsigned*)alloc((size_t)n * 128 * 2);    // feat' bf16
  int* col = (int*)alloc((size_t)n * ELL_CAP * 4);          // ELL
  unsigned* ebuf = (unsigned*)alloc((size_t)NB * BCAP * 4); // bucketed edges
  int* cnt = (int*)alloc((size_t)n * 4);
  float* dinv = (float*)alloc((size_t)n * 4);
  int* gbump = (int*)alloc(512 * 4);
  short* Wb1 = (short*)alloc(16384 * 2);
  short* Wb2 = (short*)alloc(16384 * 2);
  short* WbH = (short*)alloc(16384 * 2);
  float* bc1 = (float*)alloc(512);
  float* bc2 = (float*)alloc(512);
  float* stats = (float*)alloc(2048 * 4);

  k_prep<<<64, 256, 0, stream>>>(gbump, stats, W1g, b1g, W1s, b1s, W2g, b2g,
                                 W2s, b2s, Wf1, Wb1, Wb2, WbH, bc1, bc2, NB);
  k_bucketA<<<(E + ACHUNK - 1) / ACHUNK, 256, 0, stream>>>(srcp, dstp, gbump, ebuf, E, NB);
  k_csrB<<<NB, 256, 0, stream>>>(ebuf, gbump, cnt, dinv, col, n);
  k_xconv<<<(n * 16 + 255) / 256, 256, 0, stream>>>(x, dinv, bff, n * 16);

  unsigned* hb = (unsigned*)big1;
  unsigned short* nodesb = (unsigned short*)big1;

  // layer 1: xa = S@x; h = xa @ [W1g|W1s] + bc1 (bf16 out, BN stats fused)
  k_agg<<<(n + 7) / 8, 128, 0, stream>>>(bff, xab, cnt, dinv, col, n);
  k_mgemm<true, true><<<(n + 63) / 64, 256, 0, stream>>>(xab, Wb1, bc1, hb, n, stats);

  // layer 2: feat2' = relu(bn(h))*dinv; ha = S@feat2'; nodes = ha @ blockdiag(W2)
  k_bnfold<<<(n * 16 + 255) / 256, 256, 0, stream>>>(hb, stats, g1g, be1g, g1s,
                                                     be1s, dinv, bff,
                                                     1.f / (float)n, n * 16);
  k_agg<<<(n + 7) / 8, 128, 0, stream>>>(bff, xab, cnt, dinv, col, n);
  k_mgemm<true, false><<<(n + 63) / 64, 256, 0, stream>>>(xab, Wb2, bc2, nodesb, n, nullptr);

  // fused head
  k_fhead<<<(B + 63) / 64, 256, 0, stream>>>(nodesb, users, items, WbH, Wsig,
                                             Wtc, btc, Wp, bp, out, B);
}

// Round 12
// 242.230 us; speedup vs baseline: 1.1258x; 1.1258x over previous
//
#include <hip/hip_runtime.h>
#include <hip/hip_bf16.h>

// ---------------------------------------------------------------------------
// AMMN_Net: dual 2-layer GCN + gated fusion head.
// R12 = R10 + agg/GEMM fusion per layer:
//  - k_aggemm: phase 1 = R10 agg body (16 lanes/node, 4-deep unroll, dinv
//    table) for 64 rows -> swizzled LDS tile (chunk ^= row&7, conflict-free);
//    phase 2 = MFMA GEMM reading A-fragments from LDS, W fragments from L2
//    (not LDS -> small footprint, 18.4 KB, high agg occupancy), nt-loop
//    unroll 1 with single f32x4 acc. GEMM time hides under other blocks'
//    fabric-bound agg (agg is at the ~3.4 TB/s traffic floor; proven by
//    R6/R7/R9/R10/R11 all plateauing at 64-70us, 196MB FETCH).
//  - kills xab round-trip (25.6MB) + 2 launches. nodes written to bff
//    (no overlap with hb gathers). 6 launches.
//  - rest as R10: bucketed ELL build, BN stats fused (8x-sliced), BN+ReLU
//    fused in layer-2 agg, bf16 nodes, fully fused head.
// ---------------------------------------------------------------------------

#define ELL_CAP 64
#define BCAP 8192
#define ACHUNK 5120

typedef __attribute__((ext_vector_type(8))) short short8v;   // 8 bf16
typedef __attribute__((ext_vector_type(4))) float f32x4;

static __device__ __forceinline__ unsigned short f2bf(float f) {
  unsigned u = __float_as_uint(f);
  unsigned r = (u + 0x7fffu + ((u >> 16) & 1u)) >> 16;  // RNE
  return (unsigned short)r;
}
static __device__ __forceinline__ unsigned packbf(float a, float b) {
  return (unsigned)f2bf(a) | ((unsigned)f2bf(b) << 16);
}
static __device__ __forceinline__ float bflo(unsigned u) {
  return __uint_as_float(u << 16);
}
static __device__ __forceinline__ float bfhi(unsigned u) {
  return __uint_as_float(u & 0xffff0000u);
}
static __device__ __forceinline__ float bf2f(short s) {
  return __uint_as_float((unsigned)(unsigned short)s << 16);
}

// prep: x->bf16 row-major; pack Wb1/Wb2(block-diag)/WbH bf16 [k/8][128][8];
// biases; init gbump + stats.
__global__ void k_prep(const float* __restrict__ x, unsigned* __restrict__ bff,
                       int* __restrict__ gbump, float* __restrict__ stats,
                       const float* __restrict__ W1g, const float* __restrict__ b1g,
                       const float* __restrict__ W1s, const float* __restrict__ b1s,
                       const float* __restrict__ W2g, const float* __restrict__ b2g,
                       const float* __restrict__ W2s, const float* __restrict__ b2s,
                       const float* __restrict__ Wf1,
                       short* __restrict__ Wb1, short* __restrict__ Wb2,
                       short* __restrict__ WbH, float* __restrict__ bc1,
                       float* __restrict__ bc2, int n, int NB) {
  int idx = blockIdx.x * 256 + threadIdx.x;
  int n16 = n * 16;
  if (idx < n16) {
    const float4* f4 = (const float4*)x;
    float4 a = f4[idx * 2], b = f4[idx * 2 + 1];
    uint4 o;
    o.x = packbf(a.x, a.y);
    o.y = packbf(a.z, a.w);
    o.z = packbf(b.x, b.y);
    o.w = packbf(b.z, b.w);
    ((uint4*)bff)[idx] = o;
  }
  if (idx < 16384) {
    int k = idx >> 7, c = idx & 127;
    int pi = (k >> 3) * 1024 + c * 8 + (k & 7);  // [k/8][c][k&7]
    float w1 = (c < 64) ? W1g[k * 64 + c] : W1s[k * 64 + (c - 64)];
    Wb1[pi] = (short)f2bf(w1);
    float w2 = 0.f;
    if (k < 64 && c < 64) w2 = W2g[k * 64 + c];
    else if (k >= 64 && c >= 64) w2 = W2s[(k - 64) * 64 + (c - 64)];
    Wb2[pi] = (short)f2bf(w2);
    WbH[pi] = (short)f2bf(Wf1[k * 128 + c]);
  }
  if (idx < 128) {
    bc1[idx] = (idx < 64) ? b1g[idx] : b1s[idx - 64];
    bc2[idx] = (idx < 64) ? b2g[idx] : b2s[idx - 64];
  }
  if (idx < NB) gbump[idx] = idx * BCAP;
  if (idx < 2048) stats[idx] = 0.f;
}

// Pass A: bucket edges by dst>>8 (one global atomic per block-bucket)
__global__ __launch_bounds__(256) void k_bucketA(
    const int* __restrict__ src, const int* __restrict__ dst,
    int* __restrict__ gbump, unsigned* __restrict__ ebuf, int E, int NB) {
  __shared__ int hist[512];
  __shared__ int gbase[512];
  int t = threadIdx.x;
  int e0 = blockIdx.x * ACHUNK;
  int m = min(ACHUNK, E - e0);
  for (int b = t; b < NB; b += 256) hist[b] = 0;
  __syncthreads();
  for (int i = t; i < m; i += 256) atomicAdd(&hist[dst[e0 + i] >> 8], 1);
  __syncthreads();
  for (int b = t; b < NB; b += 256) {
    gbase[b] = hist[b] ? atomicAdd(&gbump[b], hist[b]) : 0;
    hist[b] = 0;
  }
  __syncthreads();
  for (int i = t; i < m; i += 256) {
    int d = dst[e0 + i];
    int s = src[e0 + i];
    int b = d >> 8;
    int off = gbase[b] + atomicAdd(&hist[b], 1);
    if (off < (b + 1) * BCAP)
      ebuf[off] = ((unsigned)s << 8) | (unsigned)(d & 255);
  }
}

// Pass B: block-per-bucket; LDS bump -> ELL col + capped cnt + dinv
__global__ __launch_bounds__(256) void k_csrB(
    const unsigned* __restrict__ ebuf, const int* __restrict__ gbump,
    int* __restrict__ cnt, float* __restrict__ dinv, int* __restrict__ col,
    int n) {
  __shared__ int lbump[256];
  int b = blockIdx.x;
  lbump[threadIdx.x] = 0;
  __syncthreads();
  int base = b * BCAP;
  int m = min(gbump[b] - base, BCAP);
  for (int i = threadIdx.x; i < m; i += 256) {
    unsigned p = ebuf[base + i];
    int dloc = p & 255;
    int slot = atomicAdd(&lbump[dloc], 1);
    if (slot < ELL_CAP)
      col[(b * 256 + dloc) * ELL_CAP + slot] = (int)(p >> 8);
  }
  __syncthreads();
  int node = b * 256 + threadIdx.x;
  if (node < n) {
    int c = lbump[threadIdx.x];
    cnt[node] = min(c, ELL_CAP);
    dinv[node] = rsqrtf((float)(c + 1));  // true degree for norm
  }
}

// Fused aggregation + MFMA GEMM for one layer.
// Phase 1: 4 sub-batches x 16 nodes (16 lanes/node, 4-deep unroll) -> LDS
//   tile abuf[64 rows][16 chunks of 16B], chunk swizzled ^ (row&7).
// Phase 2: per-wave 16 rows; A-fragments from LDS, W fragments from L2
//   (32KB, hot); nt-loop unroll 1, single f32x4 acc; bias/stats/epilogue.
template <bool STATS, bool CBF16, bool BN>
__global__ __launch_bounds__(256) void k_aggemm(
    const unsigned* __restrict__ featb, const int* __restrict__ cnt,
    const float* __restrict__ dinv, const int* __restrict__ col,
    const short* __restrict__ Wb, const float* __restrict__ bias,
    void* __restrict__ Cvp, int n, float* __restrict__ stats,
    const float* __restrict__ g1g, const float* __restrict__ be1g,
    const float* __restrict__ g1s, const float* __restrict__ be1s,
    float inv_n) {
  __shared__ __align__(16) unsigned abuf[4096];  // 16 KB: 64 rows x 16 uint4
  __shared__ float shs[128], shq[128];
  __shared__ float sc_sh[128], sf_sh[128];
  if (STATS && threadIdx.x < 128) { shs[threadIdx.x] = 0.f; shq[threadIdx.x] = 0.f; }
  if (BN) {
    int c = threadIdx.x;
    if (c < 128) {
      float s = 0.f, q = 0.f;
#pragma unroll
      for (int k = 0; k < 8; k++) {
        s += stats[k * 256 + c];
        q += stats[k * 256 + 128 + c];
      }
      float mu = s * inv_n;
      float var = q * inv_n - mu * mu;
      float gam = (c < 64) ? g1g[c] : g1s[c - 64];
      float bet = (c < 64) ? be1g[c] : be1s[c - 64];
      float scv = gam * rsqrtf(var + 1e-5f);
      sc_sh[c] = scv;
      sf_sh[c] = bet - mu * scv;
    }
  }
  __syncthreads();

  // ---- phase 1: aggregate 64 rows into swizzled LDS ----
  {
    int t = threadIdx.x & 15;
    int ng = threadIdx.x >> 4;  // 0..15
    float sc[8], sf[8];
    if (BN) {
#pragma unroll
      for (int j = 0; j < 8; j++) {
        sc[j] = sc_sh[8 * t + j];
        sf[j] = sf_sh[8 * t + j];
      }
    }
    const uint4* f4 = (const uint4*)featb;
    uint4* ab4 = (uint4*)abuf;
    for (int sub = 0; sub < 4; sub++) {
      int r = sub * 16 + ng;
      int node = blockIdx.x * 64 + r;
      int nodec = min(node, n - 1);
      float di = dinv[nodec];
      float acc[8];
      {
        uint4 sv = f4[nodec * 16 + t];
        float f[8] = {bflo(sv.x), bfhi(sv.x), bflo(sv.y), bfhi(sv.y),
                      bflo(sv.z), bfhi(sv.z), bflo(sv.w), bfhi(sv.w)};
#pragma unroll
        for (int j = 0; j < 8; j++) {
          if (BN) f[j] = fmaxf(f[j] * sc[j] + sf[j], 0.f);
          acc[j] = f[j] * di;
        }
      }
      int m = cnt[nodec];  // capped at ELL_CAP
      const int4* cl = (const int4*)&col[nodec * ELL_CAP];
      int i = 0;
      for (; i + 4 <= m; i += 4) {
        int4 c4 = cl[i >> 2];
        int ss[4] = {c4.x, c4.y, c4.z, c4.w};
#pragma unroll
        for (int q = 0; q < 4; q++) {
          int s = ss[q];
          float w = dinv[s];
          uint4 v = f4[s * 16 + t];
          float f[8] = {bflo(v.x), bfhi(v.x), bflo(v.y), bfhi(v.y),
                        bflo(v.z), bfhi(v.z), bflo(v.w), bfhi(v.w)};
#pragma unroll
          for (int j = 0; j < 8; j++) {
            if (BN) f[j] = fmaxf(f[j] * sc[j] + sf[j], 0.f);
            acc[j] += f[j] * w;
          }
        }
      }
      for (; i < m; ++i) {
        int s = col[nodec * ELL_CAP + i];
        float w = dinv[s];
        uint4 v = f4[s * 16 + t];
        float f[8] = {bflo(v.x), bfhi(v.x), bflo(v.y), bfhi(v.y),
                      bflo(v.z), bfhi(v.z), bflo(v.w), bfhi(v.w)};
#pragma unroll
        for (int j = 0; j < 8; j++) {
          if (BN) f[j] = fmaxf(f[j] * sc[j] + sf[j], 0.f);
          acc[j] += f[j] * w;
        }
      }
      uint4 o;
      o.x = packbf(acc[0] * di, acc[1] * di);
      o.y = packbf(acc[2] * di, acc[3] * di);
      o.z = packbf(acc[4] * di, acc[5] * di);
      o.w = packbf(acc[6] * di, acc[7] * di);
      ab4[r * 16 + (t ^ (r & 7))] = o;  // swizzled store
    }
  }
  __syncthreads();

  // ---- phase 2: MFMA GEMM on the LDS tile ----
  int lane = threadIdx.x & 63;
  int wv = threadIdx.x >> 6;
  int l15 = lane & 15;
  int l4 = lane >> 4;
  int lrow = wv * 16 + l15;
  int row = blockIdx.x * 64 + lrow;
  bool valid = row < n;
  const uint4* ab4 = (const uint4*)abuf;

  short8v afr[4];
#pragma unroll
  for (int ks = 0; ks < 4; ks++)
    afr[ks] = *(const short8v*)&ab4[lrow * 16 + ((ks * 4 + l4) ^ (lrow & 7))];

#pragma unroll 1
  for (int nt = 0; nt < 8; nt++) {
    f32x4 a = (f32x4){0.f, 0.f, 0.f, 0.f};
#pragma unroll
    for (int ks = 0; ks < 4; ks++) {
      int kb = ks * 4 + l4;
      short8v w = *(const short8v*)&Wb[kb * 1024 + (nt * 16 + l15) * 8];
      a = __builtin_amdgcn_mfma_f32_16x16x32_bf16(w, afr[ks], a, 0, 0, 0);
    }
    int c0 = nt * 16 + l4 * 4;
    float o[4];
#pragma unroll
    for (int r = 0; r < 4; r++) o[r] = a[r];
    if (bias) {
      float4 bv = *(const float4*)(bias + c0);
      o[0] += bv.x; o[1] += bv.y; o[2] += bv.z; o[3] += bv.w;
    }
    if (STATS) {
      float s[4], q[4];
#pragma unroll
      for (int r = 0; r < 4; r++) {
        s[r] = valid ? o[r] : 0.f;
        q[r] = s[r] * s[r];
      }
#pragma unroll
      for (int m = 1; m < 16; m <<= 1) {
#pragma unroll
        for (int r = 0; r < 4; r++) {
          s[r] += __shfl_xor(s[r], m, 64);
          q[r] += __shfl_xor(q[r], m, 64);
        }
      }
      if (l15 == 0) {
#pragma unroll
        for (int r = 0; r < 4; r++) {
          atomicAdd(&shs[c0 + r], s[r]);
          atomicAdd(&shq[c0 + r], q[r]);
        }
      }
    }
    if (valid) {
      if (CBF16) {
        unsigned* Cb = (unsigned*)Cvp;
        uint2 p;
        p.x = packbf(o[0], o[1]);
        p.y = packbf(o[2], o[3]);
        *(uint2*)&Cb[(size_t)row * 64 + (c0 >> 1)] = p;
      } else {
        float* Cf = (float*)Cvp;
        *(float4*)&Cf[(size_t)row * 128 + c0] = make_float4(o[0], o[1], o[2], o[3]);
      }
    }
  }
  if (STATS) {
    __syncthreads();
    if (threadIdx.x < 128) {
      float* st = stats + (blockIdx.x & 7) * 256;
      atomicAdd(&st[threadIdx.x], shs[threadIdx.x]);
      atomicAdd(&st[128 + threadIdx.x], shq[threadIdx.x]);
    }
  }
}

// Fused head: both tanh-GEMMs + gate/link/tc epilogue (see R10 notes).
__global__ __launch_bounds__(256) void k_fhead(
    const unsigned short* __restrict__ nodesb,
    const int* __restrict__ users, const int* __restrict__ items,
    const short* __restrict__ WbH, const float* __restrict__ Wsig,
    const float* __restrict__ Wtc, const float* __restrict__ btc,
    const float* __restrict__ Wp, const float* __restrict__ bp,
    float* __restrict__ out, int B) {
  __shared__ short Wl[16384];
  __shared__ float WsigL[256], WpL[256], WtcL[512];
  {
    const uint4* s4 = (const uint4*)WbH;
    uint4* d4 = (uint4*)Wl;
    for (int i = threadIdx.x; i < 2048; i += 256) d4[i] = s4[i];
    if (threadIdx.x < 256) {
      WsigL[threadIdx.x] = Wsig[threadIdx.x];
      WpL[threadIdx.x] = Wp[threadIdx.x];
    }
    for (int i = threadIdx.x; i < 512; i += 256) WtcL[i] = Wtc[i];
  }
  __syncthreads();
  int lane = threadIdx.x & 63;
  int wv = threadIdx.x >> 6;
  int l15 = lane & 15;
  int l4 = lane >> 4;
  int row = blockIdx.x * 64 + wv * 16 + l15;
  int rc = min(row, B - 1);
  int u = users[rc], it = items[rc];
  const short* pu = (const short*)nodesb + u * 128;
  const short* pi = (const short*)nodesb + it * 128;

  short8v ag[4], as[4];
#pragma unroll
  for (int ks = 0; ks < 4; ks++) {
    int k = ks * 32 + l4 * 8;
    const short* pg = (ks < 2) ? (pu + k) : (pi + (k - 64));
    const short* ps = (ks < 2) ? (pu + 64 + k) : (pi + k);
    ag[ks] = *(const short8v*)pg;
    as[ks] = *(const short8v*)ps;
  }

  f32x4 a1[8], a2[8];
#pragma unroll
  for (int nt = 0; nt < 8; nt++) {
    a1[nt] = (f32x4){0.f, 0.f, 0.f, 0.f};
    a2[nt] = (f32x4){0.f, 0.f, 0.f, 0.f};
  }
#pragma unroll
  for (int nt = 0; nt < 8; nt++) {
#pragma unroll
    for (int ks = 0; ks < 4; ks++) {
      int kb = ks * 4 + l4;
      short8v w = *(const short8v*)&Wl[kb * 1024 + (nt * 16 + l15) * 8];
      a1[nt] = __builtin_amdgcn_mfma_f32_16x16x32_bf16(w, ag[ks], a1[nt], 0, 0, 0);
      a2[nt] = __builtin_amdgcn_mfma_f32_16x16x32_bf16(w, as[ks], a2[nt], 0, 0, 0);
    }
  }

  float zp = 0.f;
#pragma unroll
  for (int nt = 0; nt < 8; nt++) {
    int c0 = nt * 16 + l4 * 4;
#pragma unroll
    for (int r = 0; r < 4; r++) {
      float h1 = tanhf(a1[nt][r]);
      float h2 = tanhf(a2[nt][r]);
      a1[nt][r] = h1;
      a2[nt][r] = h2;
      zp += h1 * WsigL[c0 + r] + h2 * WsigL[128 + c0 + r];
    }
  }
  zp += __shfl_xor(zp, 16, 64);
  zp += __shfl_xor(zp, 32, 64);
  float z = 1.f / (1.f + expf(-zp));

  float p0 = 0.f, p1 = 0.f;
#pragma unroll
  for (int nt = 0; nt < 8; nt++) {
    int c0 = nt * 16 + l4 * 4;
#pragma unroll
    for (int r = 0; r < 4; r++) {
      float fu = z * a1[nt][r] + (1.f - z) * a2[nt][r];
      p0 += fu * WpL[(c0 + r) * 2];
      p1 += fu * WpL[(c0 + r) * 2 + 1];
    }
  }
  float t0 = 0.f, t1 = 0.f, t2 = 0.f, t3 = 0.f;
#pragma unroll
  for (int ks = 0; ks < 4; ks++) {
    int kbase = ks * 32 + l4 * 8;
#pragma unroll
    for (int j = 0; j < 8; j++) {
      float gv = bf2f(ag[ks][j]);
      int c = kbase + j;
      t0 += gv * WtcL[c * 4];
      t1 += gv * WtcL[c * 4 + 1];
      t2 += gv * WtcL[c * 4 + 2];
      t3 += gv * WtcL[c * 4 + 3];
    }
  }
  p0 += __shfl_xor(p0, 16, 64); p0 += __shfl_xor(p0, 32, 64);
  p1 += __shfl_xor(p1, 16, 64); p1 += __shfl_xor(p1, 32, 64);
  t0 += __shfl_xor(t0, 16, 64); t0 += __shfl_xor(t0, 32, 64);
  t1 += __shfl_xor(t1, 16, 64); t1 += __shfl_xor(t1, 32, 64);
  t2 += __shfl_xor(t2, 16, 64); t2 += __shfl_xor(t2, 32, 64);
  t3 += __shfl_xor(t3, 16, 64); t3 += __shfl_xor(t3, 32, 64);

  if (l4 == 0 && row < B) {
    out[row * 2] = p0 + bp[0];
    out[row * 2 + 1] = p1 + bp[1];
    float* go = out + 2 * B;
    go[row * 4] = t0 + btc[0];
    go[row * 4 + 1] = t1 + btc[1];
    go[row * 4 + 2] = t2 + btc[2];
    go[row * 4 + 3] = t3 + btc[3];
  }
}

extern "C" void kernel_launch(void* const* d_in, const int* in_sizes, int n_in,
                              void* d_out, int out_size, void* d_ws, size_t ws_size,
                              hipStream_t stream) {
  const float* x = (const float*)d_in[0];
  const int* ei = (const int*)d_in[1];
  const int* users = (const int*)d_in[2];
  const int* items = (const int*)d_in[3];
  const float* W1g = (const float*)d_in[4];
  const float* b1g = (const float*)d_in[5];
  const float* g1g = (const float*)d_in[6];
  const float* be1g = (const float*)d_in[7];
  const float* W2g = (const float*)d_in[8];
  const float* b2g = (const float*)d_in[9];
  const float* W1s = (const float*)d_in[10];
  const float* b1s = (const float*)d_in[11];
  const float* g1s = (const float*)d_in[12];
  const float* be1s = (const float*)d_in[13];
  const float* W2s = (const float*)d_in[14];
  const float* b2s = (const float*)d_in[15];
  const float* Wf1 = (const float*)d_in[16];
  const float* Wsig = (const float*)d_in[17];
  const float* Wtc = (const float*)d_in[18];
  const float* btc = (const float*)d_in[19];
  const float* Wp = (const float*)d_in[20];
  const float* bp = (const float*)d_in[21];

  int n = in_sizes[0] / 128;   // 100000
  int E = in_sizes[1] / 2;     // 1600000
  int B = in_sizes[2];         // 16384
  int NB = (n + 255) >> 8;     // 391
  const int* srcp = ei;
  const int* dstp = ei + E;
  float* out = (float*)d_out;

  char* w = (char*)d_ws;
  auto alloc = [&](size_t bytes) -> char* {
    char* p = w;
    w += (bytes + 255) & ~(size_t)255;
    return p;
  };
  unsigned* bff = (unsigned*)alloc((size_t)n * 128 * 2);    // x bf16 -> later nodesb
  float* big1 = (float*)alloc((size_t)n * 128 * 4);         // hb bf16
  int* col = (int*)alloc((size_t)n * ELL_CAP * 4);          // ELL
  unsigned* ebuf = (unsigned*)alloc((size_t)NB * BCAP * 4); // bucketed edges
  int* cnt = (int*)alloc((size_t)n * 4);
  float* dinv = (float*)alloc((size_t)n * 4);
  int* gbump = (int*)alloc(512 * 4);
  short* Wb1 = (short*)alloc(16384 * 2);
  short* Wb2 = (short*)alloc(16384 * 2);
  short* WbH = (short*)alloc(16384 * 2);
  float* bc1 = (float*)alloc(512);
  float* bc2 = (float*)alloc(512);
  float* stats = (float*)alloc(2048 * 4);

  k_prep<<<(n * 16 + 255) / 256, 256, 0, stream>>>(
      x, bff, gbump, stats, W1g, b1g, W1s, b1s, W2g, b2g, W2s, b2s, Wf1,
      Wb1, Wb2, WbH, bc1, bc2, n, NB);
  k_bucketA<<<(E + ACHUNK - 1) / ACHUNK, 256, 0, stream>>>(srcp, dstp, gbump, ebuf, E, NB);
  k_csrB<<<NB, 256, 0, stream>>>(ebuf, gbump, cnt, dinv, col, n);

  unsigned* hb = (unsigned*)big1;
  unsigned short* nodesb = (unsigned short*)bff;  // reuses x-bf16 space

  // layer 1 fused: h = (S@x) @ [W1g|W1s] + bc1  (bf16 out, BN stats)
  k_aggemm<true, true, false><<<(n + 63) / 64, 256, 0, stream>>>(
      bff, cnt, dinv, col, Wb1, bc1, hb, n, stats,
      nullptr, nullptr, nullptr, nullptr, 0.f);

  // layer 2 fused: nodes = (S@relu(bn(h))) @ blockdiag(W2g,W2s) + bc2 (bf16)
  k_aggemm<false, true, true><<<(n + 63) / 64, 256, 0, stream>>>(
      hb, cnt, dinv, col, Wb2, bc2, nodesb, n, stats,
      g1g, be1g, g1s, be1s, 1.f / (float)n);

  // fused head
  k_fhead<<<(B + 63) / 64, 256, 0, stream>>>(nodesb, users, items, WbH, Wsig,
                                             Wtc, btc, Wp, bp, out, B);
}